// Round 1
// baseline (351.891 us; speedup 1.0000x reference)
//
#include <hip/hip_runtime.h>

#define TPB 256

using half8  = __attribute__((ext_vector_type(8))) _Float16;
using fp16x2 = __attribute__((ext_vector_type(2))) __fp16;
using f32x4  = __attribute__((ext_vector_type(4))) float;

static __device__ __forceinline__ unsigned short h2u(_Float16 h) {
    union { _Float16 h; unsigned short u; } v; v.h = h; return v.u;
}
static __device__ __forceinline__ unsigned pkrtz(float a, float b) {
    fp16x2 h = __builtin_amdgcn_cvt_pkrtz(a, b);
    return __builtin_bit_cast(unsigned, h);
}
template <int CTRL>
static __device__ __forceinline__ float dppmov(float x) {
    return __int_as_float(__builtin_amdgcn_mov_dpp(__float_as_int(x), CTRL, 0xF, 0xF, true));
}
#define DPP_SWAP 0xB1   // quad_perm [1,0,3,2]

// ---------- kernel 1: pack fp16 features + local scan; extra block builds weight fragments ----------
__global__ __launch_bounds__(TPB) void k_prep(const float* __restrict__ x,
                                              const float* __restrict__ h_dag,
                                              const float* __restrict__ h_glob,
                                              const int* __restrict__ ptr,
                                              const int* __restrict__ job_indices,
                                              const int* __restrict__ num_exec_acts,
                                              int J, int nb,
                                              unsigned int* __restrict__ feat,
                                              int* __restrict__ bsum, int* __restrict__ jsv,
                                              const float* __restrict__ W1,
                                              const float* __restrict__ b1,
                                              const float* __restrict__ W2,
                                              const float* __restrict__ b2,
                                              const float* __restrict__ W3,
                                              const float* __restrict__ b3,
                                              const float* __restrict__ W4,
                                              uint4* __restrict__ wfrag,
                                              float4* __restrict__ bfrag)
{
    if (blockIdx.x == (unsigned)nb) {
        // ---- weight/bias fragment build (independent of scan; 64 lanes) ----
        if (threadIdx.x < 64) {
            int lane = threadIdx.x;
            int n = lane & 15, q = lane >> 4;
#pragma unroll
            for (int nt = 0; nt < 4; nt++) {
#pragma unroll
                for (int s = 0; s < 2; s++) {
                    half8 w1f, w2f;
#pragma unroll
                    for (int jj = 0; jj < 8; jj++) {
                        int ks = s * 32 + q * 8 + jj;
                        w1f[jj] = (ks < 36) ? (_Float16)W1[ks * 64 + nt * 16 + n] : (_Float16)0.0f;
                        w2f[jj] = (_Float16)W2[ks * 64 + nt * 16 + n];
                    }
                    wfrag[(nt * 2 + s) * 64 + lane]     = __builtin_bit_cast(uint4, w1f);
                    wfrag[(8 + nt * 2 + s) * 64 + lane] = __builtin_bit_cast(uint4, w2f);
                }
            }
#pragma unroll
            for (int nt = 0; nt < 2; nt++) {
#pragma unroll
                for (int s = 0; s < 2; s++) {
                    half8 w3f;
#pragma unroll
                    for (int jj = 0; jj < 8; jj++) {
                        int ks = s * 32 + q * 8 + jj;
                        w3f[jj] = (_Float16)W3[ks * 32 + nt * 16 + n];
                    }
                    wfrag[(16 + nt * 2 + s) * 64 + lane] = __builtin_bit_cast(uint4, w3f);
                }
            }
            bfrag[0 * 64 + lane] = make_float4(b1[n], b1[16 + n], b1[32 + n], b1[48 + n]);
            bfrag[1 * 64 + lane] = make_float4(b2[n], b2[16 + n], b2[32 + n], b2[48 + n]);
            bfrag[2 * 64 + lane] = make_float4(b3[n], b3[16 + n], W4[n], W4[16 + n]);
        }
        return;
    }

    __shared__ int sc[TPB];
    int j = blockIdx.x * TPB + threadIdx.x;
    int v = 0;
    if (j < J) {
        int ji   = job_indices[j];
        v        = num_exec_acts[ji];
        int node = ptr[ji];
        float f[40];
        f[0] = x[node * 5 + 0];
        f[1] = x[node * 5 + 1];
        f[2] = x[node * 5 + 2];
#pragma unroll
        for (int c = 0; c < 16; c++) f[3 + c]  = h_dag[ji * 16 + c];
#pragma unroll
        for (int c = 0; c < 16; c++) f[19 + c] = h_glob[j * 16 + c];
#pragma unroll
        for (int c = 35; c < 40; c++) f[c] = 0.0f;
        unsigned int w[20];
#pragma unroll
        for (int k = 0; k < 20; k++)
            w[k] = (unsigned)h2u((_Float16)f[2 * k]) | ((unsigned)h2u((_Float16)f[2 * k + 1]) << 16);
        uint4* dst = (uint4*)(feat + (size_t)j * 20);
#pragma unroll
        for (int qq = 0; qq < 5; qq++)
            dst[qq] = make_uint4(w[4 * qq], w[4 * qq + 1], w[4 * qq + 2], w[4 * qq + 3]);
    }
    // inclusive scan of v
    sc[threadIdx.x] = v;
    __syncthreads();
    for (int d = 1; d < TPB; d <<= 1) {
        int add = (threadIdx.x >= d) ? sc[threadIdx.x - d] : 0;
        __syncthreads();
        sc[threadIdx.x] += add;
        __syncthreads();
    }
    if (j < J) jsv[j] = ((sc[threadIdx.x] - v) << 6) | v;
    if (threadIdx.x == TPB - 1) bsum[blockIdx.x] = sc[TPB - 1];
}

// ---------- kernel 2: fused MFMA MLP with in-kernel scan + job search (no rpt array) ----------
__global__ __launch_bounds__(TPB, 5) void k_mlp_mfma(const unsigned int* __restrict__ feat,
                                                     const int* __restrict__ jsv,
                                                     const int* __restrict__ bsum,
                                                     const uint4* __restrict__ wfrag,
                                                     const float4* __restrict__ bfrag,
                                                     const float* __restrict__ b4,
                                                     float* __restrict__ out,
                                                     int T, int J, int nb, int numTiles, int chunk)
{
    __shared__ __align__(16) char smem[4 * 4096];   // one 4 KB slab per wave (reused across layers)
    __shared__ int boffs[TPB];                       // exclusive scan of bsum
    __shared__ int swin[4][64];                      // per-wave job-start window
    const int tid  = threadIdx.x;
    const int lane = tid & 63;
    const int wv   = tid >> 6;
    const int n    = lane & 15;
    const int q    = lane >> 4;
    char* slab = smem + wv * 4096;

    // ---- block-local exclusive scan of bsum (nb <= 256) ----
    {
        int v = (tid < nb) ? bsum[tid] : 0;
        boffs[tid] = v;
        __syncthreads();
        for (int d = 1; d < TPB; d <<= 1) {
            int add = (tid >= d) ? boffs[tid - d] : 0;
            __syncthreads();
            boffs[tid] += add;
            __syncthreads();
        }
        int ex = boffs[tid] - v;
        __syncthreads();
        boffs[tid] = ex;
        __syncthreads();
    }

    // ---- fragment loads: 23 coalesced 16B loads ----
    half8 bw1[4][2], bw2[4][2], bw3[2][2];
#pragma unroll
    for (int nt = 0; nt < 4; nt++)
#pragma unroll
        for (int s = 0; s < 2; s++) {
            bw1[nt][s] = __builtin_bit_cast(half8, wfrag[(nt * 2 + s) * 64 + lane]);
            bw2[nt][s] = __builtin_bit_cast(half8, wfrag[(8 + nt * 2 + s) * 64 + lane]);
        }
#pragma unroll
    for (int nt = 0; nt < 2; nt++)
#pragma unroll
        for (int s = 0; s < 2; s++)
            bw3[nt][s] = __builtin_bit_cast(half8, wfrag[(16 + nt * 2 + s) * 64 + lane]);

    float4 bf1 = bfrag[0 * 64 + lane];
    float4 bf2 = bfrag[1 * 64 + lane];
    float4 bf3 = bfrag[2 * 64 + lane];
    float bb1[4] = {bf1.x, bf1.y, bf1.z, bf1.w};
    float bb2[4] = {bf2.x, bf2.y, bf2.z, bf2.w};
    float bb3[2] = {bf3.x, bf3.y};
    const float w4a = bf3.z, w4b = bf3.w;
    const float b4v = b4[0];
    const int   swr = (n >> 1) & 7;
    const int   odd = n & 1;

    // ---- per-block contiguous tile range; per-wave incremental job cursor ----
    const int t0 = blockIdx.x * chunk;
    const int t1 = (t0 + chunk < numTiles) ? (t0 + chunk) : numTiles;

    int j_lo;
    {
        int r0 = t0 * 128 + wv * 32;
        int lo = 0, hi = nb - 1;
        while (lo < hi) {
            int mid = (lo + hi + 1) >> 1;
            if (boffs[mid] <= r0) lo = mid; else hi = mid - 1;
        }
        j_lo = lo << 8;   // first job of that prep block; jstart(j_lo)=boffs[lo] <= r0
    }

    for (int tile = t0; tile < t1; ++tile) {
        const int rowbase = tile * 128 + wv * 32;

        // advance cursor: j_lo = max j with jstart(j) <= rowbase
        for (;;) {
            int jj = j_lo + lane;
            int s  = (jj < J) ? (boffs[jj >> 8] + (jsv[jj] >> 6)) : 0x7fffffff;
            unsigned long long m = __ballot(s <= rowbase);
            if (m == ~0ULL) { j_lo += 63; continue; }
            j_lo += 63 - __builtin_clzll(m);
            break;
        }
        // load 64-job start window at cursor (covers all 32 rows since every job has >=1 row)
        {
            int jj = j_lo + lane;
            int s  = (jj < J) ? (boffs[jj >> 8] + (jsv[jj] >> 6)) : 0x7fffffff;
            swin[wv][lane] = s;
        }

        // ---- A1 fragments straight from global (job id via window binary search) ----
        half8 a1[2][2];
#pragma unroll
        for (int mt = 0; mt < 2; mt++) {
            int  rt    = rowbase + 16 * mt + n;
            bool valid = rt < T;
            int l = 0;
#pragma unroll
            for (int stp = 32; stp; stp >>= 1) {
                int cand = l + stp;
                if (cand < 64 && swin[wv][cand] <= rt) l = cand;
            }
            int j     = j_lo + l;
            if (j > J - 1) j = J - 1;
            int start = swin[wv][l];
            const uint4* fsrc = (const uint4*)(feat + (size_t)j * 20);
            uint4 g0 = fsrc[q];
            a1[mt][0] = __builtin_bit_cast(half8, g0);
            uint4 g1 = make_uint4(0, 0, 0, 0);
            if (q == 0) {
                g1 = fsrc[4];
                float fe = valid ? (float)(rt - start) * 0.02f : 0.0f;   // exec_act_idx == rt - jstart(j)
                g1.y = (g1.y & 0xffffu) | ((unsigned)h2u((_Float16)fe) << 16);
            }
            a1[mt][1] = __builtin_bit_cast(half8, g1);
        }

        // ---- layer 1 -> slab ----
#pragma unroll
        for (int mt = 0; mt < 2; mt++) {
            f32x4 acc[4];
#pragma unroll
            for (int nt = 0; nt < 4; nt++) { f32x4 c; c[0]=c[1]=c[2]=c[3]=bb1[nt]; acc[nt]=c; }
#pragma unroll
            for (int s = 0; s < 2; s++) {
#pragma unroll
                for (int nt = 0; nt < 4; nt++)
                    acc[nt] = __builtin_amdgcn_mfma_f32_16x16x32_f16(a1[mt][s], bw1[nt][s], acc[nt], 0, 0, 0);
            }
            unsigned* sl = (unsigned*)slab;
#pragma unroll
            for (int nt = 0; nt < 4; nt++) {
                float v0 = fmaxf(acc[nt][0], 0.0f), v1 = fmaxf(acc[nt][1], 0.0f);
                float v2 = fmaxf(acc[nt][2], 0.0f), v3 = fmaxf(acc[nt][3], 0.0f);
                float t0_ = dppmov<DPP_SWAP>(v0), t1_ = dppmov<DPP_SWAP>(v1);
                float t2_ = dppmov<DPP_SWAP>(v2), t3_ = dppmov<DPP_SWAP>(v3);
                unsigned u0 = pkrtz(odd ? t2_ : v0, odd ? v2 : t0_);
                unsigned u1 = pkrtz(odd ? t3_ : v1, odd ? v3 : t1_);
                int rowA = 16 * mt + 4 * q + (odd ? 2 : 0);
                int c    = 2 * nt + (n >> 3);
                int a0   = (rowA * 8 + (c ^ ((rowA >> 1) & 7))) * 4 + ((n >> 1) & 3);
                sl[a0] = u0; sl[a0 + 32] = u1;
            }
        }

        // ---- layer 2: slab -> slab (in-place; same-wave DS ops are in-order, reads precede writes) ----
#pragma unroll
        for (int mt = 0; mt < 2; mt++) {
            const int M0 = 16 * mt;
            f32x4 acc[4];
#pragma unroll
            for (int nt = 0; nt < 4; nt++) { f32x4 c; c[0]=c[1]=c[2]=c[3]=bb2[nt]; acc[nt]=c; }
#pragma unroll
            for (int s = 0; s < 2; s++) {
                half8 a = *(const half8*)(slab + ((M0 + n) * 8 + ((s * 4 + q) ^ swr)) * 16);
#pragma unroll
                for (int nt = 0; nt < 4; nt++)
                    acc[nt] = __builtin_amdgcn_mfma_f32_16x16x32_f16(a, bw2[nt][s], acc[nt], 0, 0, 0);
            }
            unsigned* sl = (unsigned*)slab;
#pragma unroll
            for (int nt = 0; nt < 4; nt++) {
                float v0 = fmaxf(acc[nt][0], 0.0f), v1 = fmaxf(acc[nt][1], 0.0f);
                float v2 = fmaxf(acc[nt][2], 0.0f), v3 = fmaxf(acc[nt][3], 0.0f);
                float t0_ = dppmov<DPP_SWAP>(v0), t1_ = dppmov<DPP_SWAP>(v1);
                float t2_ = dppmov<DPP_SWAP>(v2), t3_ = dppmov<DPP_SWAP>(v3);
                unsigned u0 = pkrtz(odd ? t2_ : v0, odd ? v2 : t0_);
                unsigned u1 = pkrtz(odd ? t3_ : v1, odd ? v3 : t1_);
                int rowA = M0 + 4 * q + (odd ? 2 : 0);
                int c    = 2 * nt + (n >> 3);
                int a0   = (rowA * 8 + (c ^ ((rowA >> 1) & 7))) * 4 + ((n >> 1) & 3);
                sl[a0] = u0; sl[a0 + 32] = u1;
            }
        }

        // ---- layer 3 + 4: slab -> scores ----
#pragma unroll
        for (int mt = 0; mt < 2; mt++) {
            const int M0 = 16 * mt;
            f32x4 acc[2];
#pragma unroll
            for (int nt = 0; nt < 2; nt++) { f32x4 c; c[0]=c[1]=c[2]=c[3]=bb3[nt]; acc[nt]=c; }
#pragma unroll
            for (int s = 0; s < 2; s++) {
                half8 a = *(const half8*)(slab + ((M0 + n) * 8 + ((s * 4 + q) ^ swr)) * 16);
#pragma unroll
                for (int nt = 0; nt < 2; nt++)
                    acc[nt] = __builtin_amdgcn_mfma_f32_16x16x32_f16(a, bw3[nt][s], acc[nt], 0, 0, 0);
            }
            f32x4 red;
#pragma unroll
            for (int r = 0; r < 4; r++)
                red[r] = fmaxf(acc[0][r], 0.0f) * w4a + fmaxf(acc[1][r], 0.0f) * w4b;
#pragma unroll
            for (int r = 0; r < 4; r++) {
                red[r] += dppmov<0x121>(red[r]);   // row_ror:1
                red[r] += dppmov<0x122>(red[r]);   // row_ror:2
                red[r] += dppmov<0x124>(red[r]);   // row_ror:4
                red[r] += dppmov<0x128>(red[r]);   // row_ror:8
            }
            int t = rowbase + M0 + q * 4 + n;
            float val = (n == 0) ? red[0] : (n == 1) ? red[1] : (n == 2) ? red[2] : red[3];
            if (n < 4 && t < T) out[t] = val + b4v;
        }
    }
}

extern "C" void kernel_launch(void* const* d_in, const int* in_sizes, int n_in,
                              void* d_out, int out_size, void* d_ws, size_t ws_size,
                              hipStream_t stream)
{
    const float* x             = (const float*)d_in[0];
    const float* h_dag         = (const float*)d_in[1];
    const float* h_glob        = (const float*)d_in[2];
    const int*   ptr           = (const int*)d_in[3];
    const int*   job_indices   = (const int*)d_in[4];
    const int*   num_exec_acts = (const int*)d_in[5];
    const float* W1 = (const float*)d_in[7];
    const float* b1 = (const float*)d_in[8];
    const float* W2 = (const float*)d_in[9];
    const float* b2 = (const float*)d_in[10];
    const float* W3 = (const float*)d_in[11];
    const float* b3 = (const float*)d_in[12];
    const float* W4 = (const float*)d_in[13];
    const float* b4 = (const float*)d_in[14];
    float* out = (float*)d_out;

    int J  = in_sizes[4];
    int T  = in_sizes[6];
    int nb = (J + TPB - 1) / TPB;

    // workspace layout
    char* wsp = (char*)d_ws;
    int* bsum = (int*)wsp;
    wsp += (((size_t)nb * 4) + 255) / 256 * 256;
    int* jsv = (int*)wsp;
    wsp += (((size_t)J * 4) + 255) / 256 * 256;
    uint4* wfrag = (uint4*)wsp;            // 20*64*16 B
    wsp += 20 * 64 * 16;
    float4* bfrag = (float4*)wsp;          // 3*64*16 B
    wsp += 3 * 64 * 16;
    unsigned int* feat = (unsigned int*)wsp;   // J*20 words

    k_prep<<<nb + 1, TPB, 0, stream>>>(x, h_dag, h_glob, ptr, job_indices, num_exec_acts,
                                       J, nb, feat, bsum, jsv,
                                       W1, b1, W2, b2, W3, b3, W4, wfrag, bfrag);

    int numTiles = (T + 127) / 128;
    int grid = numTiles < 1280 ? numTiles : 1280;
    int chunk = (numTiles + grid - 1) / grid;
    grid = (numTiles + chunk - 1) / chunk;
    k_mlp_mfma<<<grid, TPB, 0, stream>>>(feat, jsv, bsum, wfrag, bfrag, b4,
                                         out, T, J, nb, numTiles, chunk);
}

// Round 2
// 188.726 us; speedup vs baseline: 1.8646x; 1.8646x over previous
//
#include <hip/hip_runtime.h>

#define TPB 256

using half8  = __attribute__((ext_vector_type(8))) _Float16;
using fp16x2 = __attribute__((ext_vector_type(2))) __fp16;
using f32x4  = __attribute__((ext_vector_type(4))) float;

static __device__ __forceinline__ unsigned short h2u(_Float16 h) {
    union { _Float16 h; unsigned short u; } v; v.h = h; return v.u;
}
static __device__ __forceinline__ unsigned pkrtz(float a, float b) {
    fp16x2 h = __builtin_amdgcn_cvt_pkrtz(a, b);
    return __builtin_bit_cast(unsigned, h);
}
template <int CTRL>
static __device__ __forceinline__ float dppmov(float x) {
    return __int_as_float(__builtin_amdgcn_mov_dpp(__float_as_int(x), CTRL, 0xF, 0xF, true));
}
#define DPP_SWAP 0xB1   // quad_perm [1,0,3,2]

// ---------- kernel 1: pack fp16 features + local scan; extra block builds weight fragments ----------
__global__ __launch_bounds__(TPB) void k_prep(const float* __restrict__ x,
                                              const float* __restrict__ h_dag,
                                              const float* __restrict__ h_glob,
                                              const int* __restrict__ ptr,
                                              const int* __restrict__ job_indices,
                                              const int* __restrict__ num_exec_acts,
                                              int J, int nb,
                                              unsigned int* __restrict__ feat,
                                              int* __restrict__ bsum, int* __restrict__ jsv,
                                              const float* __restrict__ W1,
                                              const float* __restrict__ b1,
                                              const float* __restrict__ W2,
                                              const float* __restrict__ b2,
                                              const float* __restrict__ W3,
                                              const float* __restrict__ b3,
                                              const float* __restrict__ W4,
                                              uint4* __restrict__ wfrag,
                                              float4* __restrict__ bfrag)
{
    if (blockIdx.x == (unsigned)nb) {
        // ---- weight/bias fragment build (independent of scan; 64 lanes) ----
        if (threadIdx.x < 64) {
            int lane = threadIdx.x;
            int n = lane & 15, q = lane >> 4;
#pragma unroll
            for (int nt = 0; nt < 4; nt++) {
#pragma unroll
                for (int s = 0; s < 2; s++) {
                    half8 w1f, w2f;
#pragma unroll
                    for (int jj = 0; jj < 8; jj++) {
                        int ks = s * 32 + q * 8 + jj;
                        w1f[jj] = (ks < 36) ? (_Float16)W1[ks * 64 + nt * 16 + n] : (_Float16)0.0f;
                        w2f[jj] = (_Float16)W2[ks * 64 + nt * 16 + n];
                    }
                    wfrag[(nt * 2 + s) * 64 + lane]     = __builtin_bit_cast(uint4, w1f);
                    wfrag[(8 + nt * 2 + s) * 64 + lane] = __builtin_bit_cast(uint4, w2f);
                }
            }
#pragma unroll
            for (int nt = 0; nt < 2; nt++) {
#pragma unroll
                for (int s = 0; s < 2; s++) {
                    half8 w3f;
#pragma unroll
                    for (int jj = 0; jj < 8; jj++) {
                        int ks = s * 32 + q * 8 + jj;
                        w3f[jj] = (_Float16)W3[ks * 32 + nt * 16 + n];
                    }
                    wfrag[(16 + nt * 2 + s) * 64 + lane] = __builtin_bit_cast(uint4, w3f);
                }
            }
            bfrag[0 * 64 + lane] = make_float4(b1[n], b1[16 + n], b1[32 + n], b1[48 + n]);
            bfrag[1 * 64 + lane] = make_float4(b2[n], b2[16 + n], b2[32 + n], b2[48 + n]);
            bfrag[2 * 64 + lane] = make_float4(b3[n], b3[16 + n], W4[n], W4[16 + n]);
        }
        return;
    }

    __shared__ int sc[TPB];
    int j = blockIdx.x * TPB + threadIdx.x;
    int v = 0;
    if (j < J) {
        int ji   = job_indices[j];
        v        = num_exec_acts[ji];
        int node = ptr[ji];
        float f[40];
        f[0] = x[node * 5 + 0];
        f[1] = x[node * 5 + 1];
        f[2] = x[node * 5 + 2];
#pragma unroll
        for (int c = 0; c < 16; c++) f[3 + c]  = h_dag[ji * 16 + c];
#pragma unroll
        for (int c = 0; c < 16; c++) f[19 + c] = h_glob[j * 16 + c];
#pragma unroll
        for (int c = 35; c < 40; c++) f[c] = 0.0f;
        unsigned int w[20];
#pragma unroll
        for (int k = 0; k < 20; k++)
            w[k] = (unsigned)h2u((_Float16)f[2 * k]) | ((unsigned)h2u((_Float16)f[2 * k + 1]) << 16);
        uint4* dst = (uint4*)(feat + (size_t)j * 20);
#pragma unroll
        for (int qq = 0; qq < 5; qq++)
            dst[qq] = make_uint4(w[4 * qq], w[4 * qq + 1], w[4 * qq + 2], w[4 * qq + 3]);
    }
    // inclusive scan of v
    sc[threadIdx.x] = v;
    __syncthreads();
    for (int d = 1; d < TPB; d <<= 1) {
        int add = (threadIdx.x >= d) ? sc[threadIdx.x - d] : 0;
        __syncthreads();
        sc[threadIdx.x] += add;
        __syncthreads();
    }
    if (j < J) jsv[j] = ((sc[threadIdx.x] - v) << 6) | v;
    if (threadIdx.x == TPB - 1) bsum[blockIdx.x] = sc[TPB - 1];
}

// ---------- kernel 2: fused MFMA MLP with in-kernel scan + job search (no rpt array) ----------
__global__ __launch_bounds__(TPB) void k_mlp_mfma(const unsigned int* __restrict__ feat,
                                                  const int* __restrict__ jsv,
                                                  const int* __restrict__ bsum,
                                                  const uint4* __restrict__ wfrag,
                                                  const float4* __restrict__ bfrag,
                                                  const float* __restrict__ b4,
                                                  float* __restrict__ out,
                                                  int T, int J, int nb, int numTiles, int chunk)
{
    __shared__ __align__(16) char smem[4 * 4096];   // one 4 KB slab per wave (reused across layers)
    __shared__ int boffs[TPB];                       // exclusive scan of bsum
    __shared__ int swin[4][64];                      // per-wave job-start window
    const int tid  = threadIdx.x;
    const int lane = tid & 63;
    const int wv   = tid >> 6;
    const int n    = lane & 15;
    const int q    = lane >> 4;
    char* slab = smem + wv * 4096;

    // ---- block-local exclusive scan of bsum (nb <= 256) ----
    {
        int v = (tid < nb) ? bsum[tid] : 0;
        boffs[tid] = v;
        __syncthreads();
        for (int d = 1; d < TPB; d <<= 1) {
            int add = (tid >= d) ? boffs[tid - d] : 0;
            __syncthreads();
            boffs[tid] += add;
            __syncthreads();
        }
        int ex = boffs[tid] - v;
        __syncthreads();
        boffs[tid] = ex;
        __syncthreads();
    }

    // ---- fragment loads: 23 coalesced 16B loads ----
    half8 bw1[4][2], bw2[4][2], bw3[2][2];
#pragma unroll
    for (int nt = 0; nt < 4; nt++)
#pragma unroll
        for (int s = 0; s < 2; s++) {
            bw1[nt][s] = __builtin_bit_cast(half8, wfrag[(nt * 2 + s) * 64 + lane]);
            bw2[nt][s] = __builtin_bit_cast(half8, wfrag[(8 + nt * 2 + s) * 64 + lane]);
        }
#pragma unroll
    for (int nt = 0; nt < 2; nt++)
#pragma unroll
        for (int s = 0; s < 2; s++)
            bw3[nt][s] = __builtin_bit_cast(half8, wfrag[(16 + nt * 2 + s) * 64 + lane]);

    float4 bf1 = bfrag[0 * 64 + lane];
    float4 bf2 = bfrag[1 * 64 + lane];
    float4 bf3 = bfrag[2 * 64 + lane];
    float bb1[4] = {bf1.x, bf1.y, bf1.z, bf1.w};
    float bb2[4] = {bf2.x, bf2.y, bf2.z, bf2.w};
    float bb3[2] = {bf3.x, bf3.y};
    const float w4a = bf3.z, w4b = bf3.w;
    const float b4v = b4[0];
    const int   swr = (n >> 1) & 7;
    const int   odd = n & 1;

    // ---- per-block contiguous tile range; per-wave incremental job cursor ----
    const int t0 = blockIdx.x * chunk;
    const int t1 = (t0 + chunk < numTiles) ? (t0 + chunk) : numTiles;

    int j_lo;
    {
        int r0 = t0 * 128 + wv * 32;
        int lo = 0, hi = nb - 1;
        while (lo < hi) {
            int mid = (lo + hi + 1) >> 1;
            if (boffs[mid] <= r0) lo = mid; else hi = mid - 1;
        }
        j_lo = lo << 8;   // first job of that prep block; jstart(j_lo)=boffs[lo] <= r0
    }

    for (int tile = t0; tile < t1; ++tile) {
        const int rowbase = tile * 128 + wv * 32;

        // advance cursor: j_lo = max j with jstart(j) <= rowbase
        for (;;) {
            int jj = j_lo + lane;
            int s  = (jj < J) ? (boffs[jj >> 8] + (jsv[jj] >> 6)) : 0x7fffffff;
            unsigned long long m = __ballot(s <= rowbase);
            if (m == ~0ULL) { j_lo += 63; continue; }
            j_lo += 63 - __builtin_clzll(m);
            break;
        }
        // load 64-job start window at cursor (covers all 32 rows since every job has >=1 row)
        {
            int jj = j_lo + lane;
            int s  = (jj < J) ? (boffs[jj >> 8] + (jsv[jj] >> 6)) : 0x7fffffff;
            swin[wv][lane] = s;
        }

        // ---- A1 fragments straight from global (job id via window binary search) ----
        half8 a1[2][2];
#pragma unroll
        for (int mt = 0; mt < 2; mt++) {
            int  rt    = rowbase + 16 * mt + n;
            bool valid = rt < T;
            int l = 0;
#pragma unroll
            for (int stp = 32; stp; stp >>= 1) {
                int cand = l + stp;
                if (cand < 64 && swin[wv][cand] <= rt) l = cand;
            }
            int j     = j_lo + l;
            if (j > J - 1) j = J - 1;
            int start = swin[wv][l];
            const uint4* fsrc = (const uint4*)(feat + (size_t)j * 20);
            uint4 g0 = fsrc[q];
            a1[mt][0] = __builtin_bit_cast(half8, g0);
            uint4 g1 = make_uint4(0, 0, 0, 0);
            if (q == 0) {
                g1 = fsrc[4];
                float fe = valid ? (float)(rt - start) * 0.02f : 0.0f;   // exec_act_idx == rt - jstart(j)
                g1.y = (g1.y & 0xffffu) | ((unsigned)h2u((_Float16)fe) << 16);
            }
            a1[mt][1] = __builtin_bit_cast(half8, g1);
        }

        // ---- layer 1 -> slab ----
#pragma unroll
        for (int mt = 0; mt < 2; mt++) {
            f32x4 acc[4];
#pragma unroll
            for (int nt = 0; nt < 4; nt++) { f32x4 c; c[0]=c[1]=c[2]=c[3]=bb1[nt]; acc[nt]=c; }
#pragma unroll
            for (int s = 0; s < 2; s++) {
#pragma unroll
                for (int nt = 0; nt < 4; nt++)
                    acc[nt] = __builtin_amdgcn_mfma_f32_16x16x32_f16(a1[mt][s], bw1[nt][s], acc[nt], 0, 0, 0);
            }
            unsigned* sl = (unsigned*)slab;
#pragma unroll
            for (int nt = 0; nt < 4; nt++) {
                float v0 = fmaxf(acc[nt][0], 0.0f), v1 = fmaxf(acc[nt][1], 0.0f);
                float v2 = fmaxf(acc[nt][2], 0.0f), v3 = fmaxf(acc[nt][3], 0.0f);
                float t0_ = dppmov<DPP_SWAP>(v0), t1_ = dppmov<DPP_SWAP>(v1);
                float t2_ = dppmov<DPP_SWAP>(v2), t3_ = dppmov<DPP_SWAP>(v3);
                unsigned u0 = pkrtz(odd ? t2_ : v0, odd ? v2 : t0_);
                unsigned u1 = pkrtz(odd ? t3_ : v1, odd ? v3 : t1_);
                int rowA = 16 * mt + 4 * q + (odd ? 2 : 0);
                int c    = 2 * nt + (n >> 3);
                int a0   = (rowA * 8 + (c ^ ((rowA >> 1) & 7))) * 4 + ((n >> 1) & 3);
                sl[a0] = u0; sl[a0 + 32] = u1;
            }
        }

        // ---- layer 2: slab -> slab (in-place; same-wave DS ops are in-order, reads precede writes) ----
#pragma unroll
        for (int mt = 0; mt < 2; mt++) {
            const int M0 = 16 * mt;
            f32x4 acc[4];
#pragma unroll
            for (int nt = 0; nt < 4; nt++) { f32x4 c; c[0]=c[1]=c[2]=c[3]=bb2[nt]; acc[nt]=c; }
#pragma unroll
            for (int s = 0; s < 2; s++) {
                half8 a = *(const half8*)(slab + ((M0 + n) * 8 + ((s * 4 + q) ^ swr)) * 16);
#pragma unroll
                for (int nt = 0; nt < 4; nt++)
                    acc[nt] = __builtin_amdgcn_mfma_f32_16x16x32_f16(a, bw2[nt][s], acc[nt], 0, 0, 0);
            }
            unsigned* sl = (unsigned*)slab;
#pragma unroll
            for (int nt = 0; nt < 4; nt++) {
                float v0 = fmaxf(acc[nt][0], 0.0f), v1 = fmaxf(acc[nt][1], 0.0f);
                float v2 = fmaxf(acc[nt][2], 0.0f), v3 = fmaxf(acc[nt][3], 0.0f);
                float t0_ = dppmov<DPP_SWAP>(v0), t1_ = dppmov<DPP_SWAP>(v1);
                float t2_ = dppmov<DPP_SWAP>(v2), t3_ = dppmov<DPP_SWAP>(v3);
                unsigned u0 = pkrtz(odd ? t2_ : v0, odd ? v2 : t0_);
                unsigned u1 = pkrtz(odd ? t3_ : v1, odd ? v3 : t1_);
                int rowA = M0 + 4 * q + (odd ? 2 : 0);
                int c    = 2 * nt + (n >> 3);
                int a0   = (rowA * 8 + (c ^ ((rowA >> 1) & 7))) * 4 + ((n >> 1) & 3);
                sl[a0] = u0; sl[a0 + 32] = u1;
            }
        }

        // ---- layer 3 + 4: slab -> scores ----
#pragma unroll
        for (int mt = 0; mt < 2; mt++) {
            const int M0 = 16 * mt;
            f32x4 acc[2];
#pragma unroll
            for (int nt = 0; nt < 2; nt++) { f32x4 c; c[0]=c[1]=c[2]=c[3]=bb3[nt]; acc[nt]=c; }
#pragma unroll
            for (int s = 0; s < 2; s++) {
                half8 a = *(const half8*)(slab + ((M0 + n) * 8 + ((s * 4 + q) ^ swr)) * 16);
#pragma unroll
                for (int nt = 0; nt < 2; nt++)
                    acc[nt] = __builtin_amdgcn_mfma_f32_16x16x32_f16(a, bw3[nt][s], acc[nt], 0, 0, 0);
            }
            f32x4 red;
#pragma unroll
            for (int r = 0; r < 4; r++)
                red[r] = fmaxf(acc[0][r], 0.0f) * w4a + fmaxf(acc[1][r], 0.0f) * w4b;
#pragma unroll
            for (int r = 0; r < 4; r++) {
                red[r] += dppmov<0x121>(red[r]);   // row_ror:1
                red[r] += dppmov<0x122>(red[r]);   // row_ror:2
                red[r] += dppmov<0x124>(red[r]);   // row_ror:4
                red[r] += dppmov<0x128>(red[r]);   // row_ror:8
            }
            int t = rowbase + M0 + q * 4 + n;
            float val = (n == 0) ? red[0] : (n == 1) ? red[1] : (n == 2) ? red[2] : red[3];
            if (n < 4 && t < T) out[t] = val + b4v;
        }
    }
}

extern "C" void kernel_launch(void* const* d_in, const int* in_sizes, int n_in,
                              void* d_out, int out_size, void* d_ws, size_t ws_size,
                              hipStream_t stream)
{
    const float* x             = (const float*)d_in[0];
    const float* h_dag         = (const float*)d_in[1];
    const float* h_glob        = (const float*)d_in[2];
    const int*   ptr           = (const int*)d_in[3];
    const int*   job_indices   = (const int*)d_in[4];
    const int*   num_exec_acts = (const int*)d_in[5];
    const float* W1 = (const float*)d_in[7];
    const float* b1 = (const float*)d_in[8];
    const float* W2 = (const float*)d_in[9];
    const float* b2 = (const float*)d_in[10];
    const float* W3 = (const float*)d_in[11];
    const float* b3 = (const float*)d_in[12];
    const float* W4 = (const float*)d_in[13];
    const float* b4 = (const float*)d_in[14];
    float* out = (float*)d_out;

    int J  = in_sizes[4];
    int T  = in_sizes[6];
    int nb = (J + TPB - 1) / TPB;

    // workspace layout
    char* wsp = (char*)d_ws;
    int* bsum = (int*)wsp;
    wsp += (((size_t)nb * 4) + 255) / 256 * 256;
    int* jsv = (int*)wsp;
    wsp += (((size_t)J * 4) + 255) / 256 * 256;
    uint4* wfrag = (uint4*)wsp;            // 20*64*16 B
    wsp += 20 * 64 * 16;
    float4* bfrag = (float4*)wsp;          // 3*64*16 B
    wsp += 3 * 64 * 16;
    unsigned int* feat = (unsigned int*)wsp;   // J*20 words

    k_prep<<<nb + 1, TPB, 0, stream>>>(x, h_dag, h_glob, ptr, job_indices, num_exec_acts,
                                       J, nb, feat, bsum, jsv,
                                       W1, b1, W2, b2, W3, b3, W4, wfrag, bfrag);

    int numTiles = (T + 127) / 128;
    int grid = numTiles < 1280 ? numTiles : 1280;
    int chunk = (numTiles + grid - 1) / grid;
    grid = (numTiles + chunk - 1) / chunk;
    k_mlp_mfma<<<grid, TPB, 0, stream>>>(feat, jsv, bsum, wfrag, bfrag, b4,
                                         out, T, J, nb, numTiles, chunk);
}

// Round 3
// 181.377 us; speedup vs baseline: 1.9401x; 1.0405x over previous
//
#include <hip/hip_runtime.h>

#define TPB 256

using half8  = __attribute__((ext_vector_type(8))) _Float16;
using fp16x2 = __attribute__((ext_vector_type(2))) __fp16;
using f32x4  = __attribute__((ext_vector_type(4))) float;

static __device__ __forceinline__ unsigned short h2u(_Float16 h) {
    union { _Float16 h; unsigned short u; } v; v.h = h; return v.u;
}
static __device__ __forceinline__ unsigned pkrtz(float a, float b) {
    fp16x2 h = __builtin_amdgcn_cvt_pkrtz(a, b);
    return __builtin_bit_cast(unsigned, h);
}
template <int CTRL>
static __device__ __forceinline__ float dppmov(float x) {
    return __int_as_float(__builtin_amdgcn_mov_dpp(__float_as_int(x), CTRL, 0xF, 0xF, true));
}
#define DPP_SWAP 0xB1   // quad_perm [1,0,3,2]

// ---------- kernel 1: pack fp16 features + local scan; extra block builds weight fragments ----------
__global__ __launch_bounds__(TPB) void k_prep(const float* __restrict__ x,
                                              const float* __restrict__ h_dag,
                                              const float* __restrict__ h_glob,
                                              const int* __restrict__ ptr,
                                              const int* __restrict__ job_indices,
                                              const int* __restrict__ num_exec_acts,
                                              int J, int nb,
                                              unsigned int* __restrict__ feat,
                                              int* __restrict__ bsum, int* __restrict__ jsv,
                                              const float* __restrict__ W1,
                                              const float* __restrict__ b1,
                                              const float* __restrict__ W2,
                                              const float* __restrict__ b2,
                                              const float* __restrict__ W3,
                                              const float* __restrict__ b3,
                                              const float* __restrict__ W4,
                                              uint4* __restrict__ wfrag,
                                              float4* __restrict__ bfrag)
{
    if (blockIdx.x == (unsigned)nb) {
        // ---- weight/bias fragment build (independent of scan; 64 lanes) ----
        if (threadIdx.x < 64) {
            int lane = threadIdx.x;
            int n = lane & 15, q = lane >> 4;
#pragma unroll
            for (int nt = 0; nt < 4; nt++) {
#pragma unroll
                for (int s = 0; s < 2; s++) {
                    half8 w1f, w2f;
#pragma unroll
                    for (int jj = 0; jj < 8; jj++) {
                        int ks = s * 32 + q * 8 + jj;
                        w1f[jj] = (ks < 36) ? (_Float16)W1[ks * 64 + nt * 16 + n] : (_Float16)0.0f;
                        w2f[jj] = (_Float16)W2[ks * 64 + nt * 16 + n];
                    }
                    wfrag[(nt * 2 + s) * 64 + lane]     = __builtin_bit_cast(uint4, w1f);
                    wfrag[(8 + nt * 2 + s) * 64 + lane] = __builtin_bit_cast(uint4, w2f);
                }
            }
#pragma unroll
            for (int nt = 0; nt < 2; nt++) {
#pragma unroll
                for (int s = 0; s < 2; s++) {
                    half8 w3f;
#pragma unroll
                    for (int jj = 0; jj < 8; jj++) {
                        int ks = s * 32 + q * 8 + jj;
                        w3f[jj] = (_Float16)W3[ks * 32 + nt * 16 + n];
                    }
                    wfrag[(16 + nt * 2 + s) * 64 + lane] = __builtin_bit_cast(uint4, w3f);
                }
            }
            bfrag[0 * 64 + lane] = make_float4(b1[n], b1[16 + n], b1[32 + n], b1[48 + n]);
            bfrag[1 * 64 + lane] = make_float4(b2[n], b2[16 + n], b2[32 + n], b2[48 + n]);
            bfrag[2 * 64 + lane] = make_float4(b3[n], b3[16 + n], W4[n], W4[16 + n]);
        }
        return;
    }

    __shared__ int sc[TPB];
    int j = blockIdx.x * TPB + threadIdx.x;
    int v = 0;
    if (j < J) {
        int ji   = job_indices[j];
        v        = num_exec_acts[ji];
        int node = ptr[ji];
        float f[40];
        f[0] = x[node * 5 + 0];
        f[1] = x[node * 5 + 1];
        f[2] = x[node * 5 + 2];
        // vectorized gathers: ji*16 floats = 64B aligned
        float4 hd[4], hg[4];
#pragma unroll
        for (int c4 = 0; c4 < 4; c4++) hd[c4] = *(const float4*)(h_dag + (size_t)ji * 16 + 4 * c4);
#pragma unroll
        for (int c4 = 0; c4 < 4; c4++) hg[c4] = *(const float4*)(h_glob + (size_t)j * 16 + 4 * c4);
#pragma unroll
        for (int c4 = 0; c4 < 4; c4++) {
            f[3 + 4 * c4 + 0]  = hd[c4].x; f[3 + 4 * c4 + 1]  = hd[c4].y;
            f[3 + 4 * c4 + 2]  = hd[c4].z; f[3 + 4 * c4 + 3]  = hd[c4].w;
            f[19 + 4 * c4 + 0] = hg[c4].x; f[19 + 4 * c4 + 1] = hg[c4].y;
            f[19 + 4 * c4 + 2] = hg[c4].z; f[19 + 4 * c4 + 3] = hg[c4].w;
        }
#pragma unroll
        for (int c = 35; c < 40; c++) f[c] = 0.0f;
        unsigned int w[20];
#pragma unroll
        for (int k = 0; k < 20; k++)
            w[k] = (unsigned)h2u((_Float16)f[2 * k]) | ((unsigned)h2u((_Float16)f[2 * k + 1]) << 16);
        uint4* dst = (uint4*)(feat + (size_t)j * 20);
#pragma unroll
        for (int qq = 0; qq < 5; qq++)
            dst[qq] = make_uint4(w[4 * qq], w[4 * qq + 1], w[4 * qq + 2], w[4 * qq + 3]);
    }
    // inclusive scan of v
    sc[threadIdx.x] = v;
    __syncthreads();
    for (int d = 1; d < TPB; d <<= 1) {
        int add = (threadIdx.x >= d) ? sc[threadIdx.x - d] : 0;
        __syncthreads();
        sc[threadIdx.x] += add;
        __syncthreads();
    }
    if (j < J) jsv[j] = ((sc[threadIdx.x] - v) << 6) | v;
    if (threadIdx.x == TPB - 1) bsum[blockIdx.x] = sc[TPB - 1];
}

// ---------- kernel 2: fused MFMA MLP; per-wave contiguous rows + amortized job window ----------
__global__ __launch_bounds__(TPB) void k_mlp_mfma(const unsigned int* __restrict__ feat,
                                                  const int* __restrict__ jsv,
                                                  const int* __restrict__ bsum,
                                                  const uint4* __restrict__ wfrag,
                                                  const float4* __restrict__ bfrag,
                                                  const float* __restrict__ b4,
                                                  float* __restrict__ out,
                                                  int T, int J, int nb, int numTiles, int chunk)
{
    __shared__ __align__(16) char smem[4 * 4096];   // one 4 KB slab per wave (reused across layers)
    __shared__ int boffs[TPB];                       // exclusive scan of bsum
    __shared__ int swin[4][64];                      // per-wave job-start window
    __shared__ int srow[4][32];                      // per-wave per-row (job<<8|exec) for current 32 rows
    const int tid  = threadIdx.x;
    const int lane = tid & 63;
    const int wv   = tid >> 6;
    const int n    = lane & 15;
    const int q    = lane >> 4;
    char* slab = smem + wv * 4096;

    // ---- block-local exclusive scan of bsum (nb <= 256) ----
    {
        int v = (tid < nb) ? bsum[tid] : 0;
        boffs[tid] = v;
        __syncthreads();
        for (int d = 1; d < TPB; d <<= 1) {
            int add = (tid >= d) ? boffs[tid - d] : 0;
            __syncthreads();
            boffs[tid] += add;
            __syncthreads();
        }
        int ex = boffs[tid] - v;
        __syncthreads();
        boffs[tid] = ex;
        __syncthreads();
    }

    // ---- fragment loads: 23 coalesced 16B loads ----
    half8 bw1[4][2], bw2[4][2], bw3[2][2];
#pragma unroll
    for (int nt = 0; nt < 4; nt++)
#pragma unroll
        for (int s = 0; s < 2; s++) {
            bw1[nt][s] = __builtin_bit_cast(half8, wfrag[(nt * 2 + s) * 64 + lane]);
            bw2[nt][s] = __builtin_bit_cast(half8, wfrag[(8 + nt * 2 + s) * 64 + lane]);
        }
#pragma unroll
    for (int nt = 0; nt < 2; nt++)
#pragma unroll
        for (int s = 0; s < 2; s++)
            bw3[nt][s] = __builtin_bit_cast(half8, wfrag[(16 + nt * 2 + s) * 64 + lane]);

    float4 bf1 = bfrag[0 * 64 + lane];
    float4 bf2 = bfrag[1 * 64 + lane];
    float4 bf3 = bfrag[2 * 64 + lane];
    float bb1[4] = {bf1.x, bf1.y, bf1.z, bf1.w};
    float bb2[4] = {bf2.x, bf2.y, bf2.z, bf2.w};
    float bb3[2] = {bf3.x, bf3.y};
    const float w4a = bf3.z, w4b = bf3.w;
    const float b4v = b4[0];
    const int   swr = (n >> 1) & 7;
    const int   odd = n & 1;

    // ---- per-block contiguous tile range; wave wv owns the wv-th quarter (contiguous rows) ----
    const int t0 = blockIdx.x * chunk;
    const int t1 = (t0 + chunk < numTiles) ? (t0 + chunk) : numTiles;
    const int R  = (t1 - t0) * 32;                 // rows per wave
    const int r0 = t0 * 128 + wv * R;              // first row of this wave
    int rend = r0 + R;
    if (rend > T) rend = T;

    if (r0 < rend) {
        // initial cursor: prep-block whose exclusive offset <= r0
        int j_lo;
        {
            int lo = 0, hi = nb - 1;
            while (lo < hi) {
                int mid = (lo + hi + 1) >> 1;
                if (boffs[mid] <= r0) lo = mid; else hi = mid - 1;
            }
            j_lo = lo << 8;   // jstart(j_lo) = boffs[lo] <= r0
        }
        int sreg    = 0;
        int win_top = 0x80000000;   // forces first refill

        for (int rb = r0; rb < rend; rb += 32) {
            // ---- refill job-start window when it no longer covers [rb, rb+32) ----
            if (win_top <= rb + 31) {
                for (;;) {
                    int jj = j_lo + lane;
                    sreg = (jj < J) ? (boffs[jj >> 8] + (jsv[jj] >> 6)) : 0x7fffffff;
                    unsigned long long m = __ballot(sreg <= rb);
                    int adv = 63 - __builtin_clzll(m);   // bit0 always set (invariant)
                    j_lo += adv;
                    if (adv == 0) break;
                }
                swin[wv][lane] = sreg;
                win_top = __shfl(sreg, 63);
            }

            // ---- half-wave per-row search: lanes 0..31 resolve rows rb..rb+31 ----
            if (lane < 32) {
                int rt = rb + lane;
                const int* sw = swin[wv];
                int lj = 0;
#pragma unroll
                for (int stp = 32; stp; stp >>= 1) {
                    int c = lj + stp;
                    if (c < 64 && sw[c] <= rt) lj = c;
                }
                srow[wv][lane] = (lj << 8) | (rt - sw[lj]);   // exec fits 8 bits (<=~80)
            }
            // same-wave LDS: DS pipe is in-order, no barrier needed

            // ---- A1 fragments straight from global ----
            half8 a1[2][2];
#pragma unroll
            for (int mt = 0; mt < 2; mt++) {
                int  rt    = rb + 16 * mt + n;
                bool valid = rt < T;
                int  u     = srow[wv][16 * mt + n];
                int  jj2   = j_lo + (u >> 8);
                const uint4* fsrc = (const uint4*)(feat + (size_t)jj2 * 20);
                uint4 g0 = fsrc[q];
                a1[mt][0] = __builtin_bit_cast(half8, g0);
                uint4 g1 = make_uint4(0, 0, 0, 0);
                if (q == 0) {
                    g1 = fsrc[4];
                    float fe = valid ? (float)(u & 255) * 0.02f : 0.0f;  // exec_act_idx == rt - jstart
                    g1.y = (g1.y & 0xffffu) | ((unsigned)h2u((_Float16)fe) << 16);
                }
                a1[mt][1] = __builtin_bit_cast(half8, g1);
            }

            // ---- layer 1 -> slab ----
#pragma unroll
            for (int mt = 0; mt < 2; mt++) {
                f32x4 acc[4];
#pragma unroll
                for (int nt = 0; nt < 4; nt++) { f32x4 c; c[0]=c[1]=c[2]=c[3]=bb1[nt]; acc[nt]=c; }
#pragma unroll
                for (int s = 0; s < 2; s++) {
#pragma unroll
                    for (int nt = 0; nt < 4; nt++)
                        acc[nt] = __builtin_amdgcn_mfma_f32_16x16x32_f16(a1[mt][s], bw1[nt][s], acc[nt], 0, 0, 0);
                }
                unsigned* sl = (unsigned*)slab;
#pragma unroll
                for (int nt = 0; nt < 4; nt++) {
                    float v0 = fmaxf(acc[nt][0], 0.0f), v1 = fmaxf(acc[nt][1], 0.0f);
                    float v2 = fmaxf(acc[nt][2], 0.0f), v3 = fmaxf(acc[nt][3], 0.0f);
                    float t0_ = dppmov<DPP_SWAP>(v0), t1_ = dppmov<DPP_SWAP>(v1);
                    float t2_ = dppmov<DPP_SWAP>(v2), t3_ = dppmov<DPP_SWAP>(v3);
                    unsigned u0 = pkrtz(odd ? t2_ : v0, odd ? v2 : t0_);
                    unsigned u1 = pkrtz(odd ? t3_ : v1, odd ? v3 : t1_);
                    int rowA = 16 * mt + 4 * q + (odd ? 2 : 0);
                    int c    = 2 * nt + (n >> 3);
                    int a0   = (rowA * 8 + (c ^ ((rowA >> 1) & 7))) * 4 + ((n >> 1) & 3);
                    sl[a0] = u0; sl[a0 + 32] = u1;
                }
            }

            // ---- layer 2: slab -> slab (in-place; same-wave DS ops are in-order) ----
#pragma unroll
            for (int mt = 0; mt < 2; mt++) {
                const int M0 = 16 * mt;
                f32x4 acc[4];
#pragma unroll
                for (int nt = 0; nt < 4; nt++) { f32x4 c; c[0]=c[1]=c[2]=c[3]=bb2[nt]; acc[nt]=c; }
#pragma unroll
                for (int s = 0; s < 2; s++) {
                    half8 a = *(const half8*)(slab + ((M0 + n) * 8 + ((s * 4 + q) ^ swr)) * 16);
#pragma unroll
                    for (int nt = 0; nt < 4; nt++)
                        acc[nt] = __builtin_amdgcn_mfma_f32_16x16x32_f16(a, bw2[nt][s], acc[nt], 0, 0, 0);
                }
                unsigned* sl = (unsigned*)slab;
#pragma unroll
                for (int nt = 0; nt < 4; nt++) {
                    float v0 = fmaxf(acc[nt][0], 0.0f), v1 = fmaxf(acc[nt][1], 0.0f);
                    float v2 = fmaxf(acc[nt][2], 0.0f), v3 = fmaxf(acc[nt][3], 0.0f);
                    float t0_ = dppmov<DPP_SWAP>(v0), t1_ = dppmov<DPP_SWAP>(v1);
                    float t2_ = dppmov<DPP_SWAP>(v2), t3_ = dppmov<DPP_SWAP>(v3);
                    unsigned u0 = pkrtz(odd ? t2_ : v0, odd ? v2 : t0_);
                    unsigned u1 = pkrtz(odd ? t3_ : v1, odd ? v3 : t1_);
                    int rowA = M0 + 4 * q + (odd ? 2 : 0);
                    int c    = 2 * nt + (n >> 3);
                    int a0   = (rowA * 8 + (c ^ ((rowA >> 1) & 7))) * 4 + ((n >> 1) & 3);
                    sl[a0] = u0; sl[a0 + 32] = u1;
                }
            }

            // ---- layer 3 + 4: slab -> scores ----
#pragma unroll
            for (int mt = 0; mt < 2; mt++) {
                const int M0 = 16 * mt;
                f32x4 acc[2];
#pragma unroll
                for (int nt = 0; nt < 2; nt++) { f32x4 c; c[0]=c[1]=c[2]=c[3]=bb3[nt]; acc[nt]=c; }
#pragma unroll
                for (int s = 0; s < 2; s++) {
                    half8 a = *(const half8*)(slab + ((M0 + n) * 8 + ((s * 4 + q) ^ swr)) * 16);
#pragma unroll
                    for (int nt = 0; nt < 2; nt++)
                        acc[nt] = __builtin_amdgcn_mfma_f32_16x16x32_f16(a, bw3[nt][s], acc[nt], 0, 0, 0);
                }
                f32x4 red;
#pragma unroll
                for (int r = 0; r < 4; r++)
                    red[r] = fmaxf(acc[0][r], 0.0f) * w4a + fmaxf(acc[1][r], 0.0f) * w4b;
#pragma unroll
                for (int r = 0; r < 4; r++) {
                    red[r] += dppmov<0x121>(red[r]);   // row_ror:1
                    red[r] += dppmov<0x122>(red[r]);   // row_ror:2
                    red[r] += dppmov<0x124>(red[r]);   // row_ror:4
                    red[r] += dppmov<0x128>(red[r]);   // row_ror:8
                }
                int t = rb + M0 + q * 4 + n;
                float val = (n == 0) ? red[0] : (n == 1) ? red[1] : (n == 2) ? red[2] : red[3];
                if (n < 4 && t < T) out[t] = val + b4v;
            }
        }
    }
}

extern "C" void kernel_launch(void* const* d_in, const int* in_sizes, int n_in,
                              void* d_out, int out_size, void* d_ws, size_t ws_size,
                              hipStream_t stream)
{
    const float* x             = (const float*)d_in[0];
    const float* h_dag         = (const float*)d_in[1];
    const float* h_glob        = (const float*)d_in[2];
    const int*   ptr           = (const int*)d_in[3];
    const int*   job_indices   = (const int*)d_in[4];
    const int*   num_exec_acts = (const int*)d_in[5];
    const float* W1 = (const float*)d_in[7];
    const float* b1 = (const float*)d_in[8];
    const float* W2 = (const float*)d_in[9];
    const float* b2 = (const float*)d_in[10];
    const float* W3 = (const float*)d_in[11];
    const float* b3 = (const float*)d_in[12];
    const float* W4 = (const float*)d_in[13];
    const float* b4 = (const float*)d_in[14];
    float* out = (float*)d_out;

    int J  = in_sizes[4];
    int T  = in_sizes[6];
    int nb = (J + TPB - 1) / TPB;

    // workspace layout
    char* wsp = (char*)d_ws;
    int* bsum = (int*)wsp;
    wsp += (((size_t)nb * 4) + 255) / 256 * 256;
    int* jsv = (int*)wsp;
    wsp += (((size_t)J * 4) + 255) / 256 * 256;
    uint4* wfrag = (uint4*)wsp;            // 20*64*16 B
    wsp += 20 * 64 * 16;
    float4* bfrag = (float4*)wsp;          // 3*64*16 B
    wsp += 3 * 64 * 16;
    unsigned int* feat = (unsigned int*)wsp;   // J*20 words

    k_prep<<<nb + 1, TPB, 0, stream>>>(x, h_dag, h_glob, ptr, job_indices, num_exec_acts,
                                       J, nb, feat, bsum, jsv,
                                       W1, b1, W2, b2, W3, b3, W4, wfrag, bfrag);

    int numTiles = (T + 127) / 128;
    int grid = numTiles < 1280 ? numTiles : 1280;
    int chunk = (numTiles + grid - 1) / grid;
    grid = (numTiles + chunk - 1) / chunk;
    k_mlp_mfma<<<grid, TPB, 0, stream>>>(feat, jsv, bsum, wfrag, bfrag, b4,
                                         out, T, J, nb, numTiles, chunk);
}